// Round 1
// baseline (277.797 us; speedup 1.0000x reference)
//
#include <hip/hip_runtime.h>
#include <hip/hip_bf16.h>

// Fused causal MHA: qkv proj -> flash attention -> out proj, all bf16 MFMA.
// B=2 T=2048 D=1024 H=16 hd=64, scale=0.125 folded into Q (exact pow2).

typedef __bf16 bf16;
typedef float f32x4 __attribute__((ext_vector_type(4)));
typedef bf16 bf16x4 __attribute__((ext_vector_type(4)));
typedef bf16 bf16x8 __attribute__((ext_vector_type(8)));

#define B_ 2
#define T_ 2048
#define D_ 1024
#define H_ 16
#define HD_ 64

__device__ __forceinline__ f32x4 mfma16(bf16x8 a, bf16x8 b, f32x4 c) {
    return __builtin_amdgcn_mfma_f32_16x16x32_bf16(a, b, c, 0, 0, 0);
}

// ---------------- cast kernels ----------------
__global__ __launch_bounds__(256) void cast_f32_bf16(const float* __restrict__ in,
                                                     bf16* __restrict__ out, int n4) {
    int i = blockIdx.x * 256 + threadIdx.x;
    if (i < n4) {
        float4 v = ((const float4*)in)[i];
        bf16x4 o = { (bf16)v.x, (bf16)v.y, (bf16)v.z, (bf16)v.w };
        ((bf16x4*)out)[i] = o;
    }
}

// in [R][C] f32 -> out [C][R] bf16
__global__ __launch_bounds__(256) void cast_transpose(const float* __restrict__ in,
                                                      bf16* __restrict__ out, int R, int C) {
    __shared__ float tile[32][33];
    int cx = blockIdx.x * 32 + threadIdx.x;
    int r0 = blockIdx.y * 32;
#pragma unroll
    for (int j = 0; j < 32; j += 8)
        tile[threadIdx.y + j][threadIdx.x] = in[(size_t)(r0 + threadIdx.y + j) * C + cx];
    __syncthreads();
    int rx = r0 + threadIdx.x;
    int c0 = blockIdx.x * 32;
#pragma unroll
    for (int j = 0; j < 32; j += 8)
        out[(size_t)(c0 + threadIdx.y + j) * R + rx] = (bf16)tile[threadIdx.x][threadIdx.y + j];
}

// ---------------- GEMM (BT form): C[M,N] = A[M,K] * Bt[N,K]^T ----------------
// EPI 0: scatter qkv into per-head Q/K/V [B][H][T][64] bf16
// EPI 1: add bias, write f32 to out
template <int EPI>
__global__ __launch_bounds__(256) void gemm_bt(
    const bf16* __restrict__ A, const bf16* __restrict__ Bt,
    int M, int N, int K,
    bf16* __restrict__ qb, bf16* __restrict__ kb, bf16* __restrict__ vb,
    const float* __restrict__ bias, float* __restrict__ outf) {
    constexpr int SAK = 40;  // padded LDS row stride (elems), 16B-aligned rows
    __shared__ bf16 sA[64 * SAK];
    __shared__ bf16 sB[64 * SAK];
    const int tid = threadIdx.x;
    const int wave = tid >> 6, lane = tid & 63;
    const int lr = lane & 15, kg4 = (lane >> 4) * 4;
    const int m0 = blockIdx.x * 64, n0 = blockIdx.y * 64;

    const int srow = tid >> 2, scol = (tid & 3) * 8;
    const bf16* gA = A + (size_t)(m0 + srow) * K + scol;
    const bf16* gB = Bt + (size_t)(n0 + srow) * K + scol;
    bf16* pA = &sA[srow * SAK + scol];
    bf16* pB = &sB[srow * SAK + scol];

    f32x4 z = {0.f, 0.f, 0.f, 0.f};
    f32x4 acc[4] = {z, z, z, z};

    for (int k0 = 0; k0 < K; k0 += 32) {
        __syncthreads();
        *(bf16x8*)pA = *(const bf16x8*)(gA + k0);
        *(bf16x8*)pB = *(const bf16x8*)(gB + k0);
        __syncthreads();
        const bf16* ra = &sA[(wave * 16 + lr) * SAK + kg4];
        bf16x4 a0 = *(const bf16x4*)ra;
        bf16x4 a1 = *(const bf16x4*)(ra + 16);
        bf16x8 af = __builtin_shufflevector(a0, a1, 0, 1, 2, 3, 4, 5, 6, 7);
#pragma unroll
        for (int nt = 0; nt < 4; ++nt) {
            const bf16* rb = &sB[(nt * 16 + lr) * SAK + kg4];
            bf16x4 b0 = *(const bf16x4*)rb;
            bf16x4 b1 = *(const bf16x4*)(rb + 16);
            bf16x8 bfr = __builtin_shufflevector(b0, b1, 0, 1, 2, 3, 4, 5, 6, 7);
            acc[nt] = mfma16(af, bfr, acc[nt]);
        }
    }

    const int orow = wave * 16 + kg4;
#pragma unroll
    for (int nt = 0; nt < 4; ++nt) {
#pragma unroll
        for (int r = 0; r < 4; ++r) {
            int row = m0 + orow + r;
            int col = n0 + nt * 16 + lr;
            float v = acc[nt][r];
            if (EPI == 0) {
                int part = col >> 10, h = (col >> 6) & 15, d = col & 63;
                int b = row >> 11, t = row & (T_ - 1);
                size_t idx = ((size_t)(b * H_ + h) * T_ + t) * HD_ + d;
                bf16* dst = (part == 0) ? qb : (part == 1) ? kb : vb;
                dst[idx] = (bf16)v;
            } else {
                outf[(size_t)row * N + col] = v + bias[col];
            }
        }
    }
}

// ---------------- flash attention ----------------
// grid: (T/64, B*H); block 256 = 4 waves, wave w owns q rows [qt*64+w*16, +16)
__global__ __launch_bounds__(256) void attn_kernel(
    const bf16* __restrict__ qb, const bf16* __restrict__ kb,
    const bf16* __restrict__ vb, bf16* __restrict__ ob) {
    constexpr int SK = 72;  // sK row stride (elems)
    constexpr int SV = 68;  // sVt row stride
    constexpr int SP = 68;  // sP row stride
    __shared__ bf16 sK[64 * SK];
    __shared__ bf16 sVt[64 * SV];
    __shared__ bf16 sP[4][16 * SP];

    const int qt = blockIdx.x, bh = blockIdx.y;
    const int b = bh >> 4, h = bh & 15;
    const int tid = threadIdx.x, wave = tid >> 6, lane = tid & 63;
    const int lr = lane & 15, kg4 = (lane >> 4) * 4;
    const size_t base = (size_t)bh * (T_ * HD_);
    const bf16* Qg = qb + base;
    const bf16* Kg = kb + base;
    const bf16* Vg = vb + base;

    // Q fragments (2 K-chunks of 32), scale 0.125 folded in (exact)
    bf16x8 qf[2];
    {
        int qrow = qt * 64 + wave * 16 + lr;
#pragma unroll
        for (int c = 0; c < 2; ++c) {
            bf16x4 q0 = *(const bf16x4*)&Qg[(size_t)qrow * 64 + c * 32 + kg4];
            bf16x4 q1 = *(const bf16x4*)&Qg[(size_t)qrow * 64 + c * 32 + 16 + kg4];
            bf16x8 q8 = __builtin_shufflevector(q0, q1, 0, 1, 2, 3, 4, 5, 6, 7);
#pragma unroll
            for (int e = 0; e < 8; ++e) q8[e] = (bf16)((float)q8[e] * 0.125f);
            qf[c] = q8;
        }
    }

    f32x4 z = {0.f, 0.f, 0.f, 0.f};
    f32x4 o[4] = {z, z, z, z};
    float m[4] = {-__builtin_inff(), -__builtin_inff(), -__builtin_inff(), -__builtin_inff()};
    float lsum[4] = {0.f, 0.f, 0.f, 0.f};

    for (int kt = 0; kt <= qt; ++kt) {
        __syncthreads();
        // stage K tile [64][64] row-major
#pragma unroll
        for (int c = 0; c < 2; ++c) {
            int cid = tid + c * 256;
            int row = cid >> 3, off = (cid & 7) * 8;
            *(bf16x8*)&sK[row * SK + off] =
                *(const bf16x8*)&Kg[(size_t)(kt * 64 + row) * 64 + off];
        }
        // stage V transposed: sVt[d][kv]
        {
            int rv = tid >> 2, d0 = (tid & 3) * 16;
            const bf16* src = &Vg[(size_t)(kt * 64 + rv) * 64 + d0];
            bf16x8 v0 = *(const bf16x8*)src;
            bf16x8 v1 = *(const bf16x8*)(src + 8);
#pragma unroll
            for (int j = 0; j < 8; ++j) {
                sVt[(d0 + j) * SV + rv] = v0[j];
                sVt[(d0 + 8 + j) * SV + rv] = v1[j];
            }
        }
        __syncthreads();

        // S = Q K^T  (D-layout: row q = kg4+r, col kv = nt*16+lr)
        f32x4 s[4] = {z, z, z, z};
#pragma unroll
        for (int c = 0; c < 2; ++c) {
#pragma unroll
            for (int nt = 0; nt < 4; ++nt) {
                const bf16* rb = &sK[(nt * 16 + lr) * SK + c * 32 + kg4];
                bf16x4 b0 = *(const bf16x4*)rb;
                bf16x4 b1 = *(const bf16x4*)(rb + 16);
                s[nt] = mfma16(qf[c],
                               __builtin_shufflevector(b0, b1, 0, 1, 2, 3, 4, 5, 6, 7),
                               s[nt]);
            }
        }

        // causal mask (only diagonal tile)
        if (kt == qt) {
#pragma unroll
            for (int nt = 0; nt < 4; ++nt)
#pragma unroll
                for (int r = 0; r < 4; ++r)
                    if (nt * 16 + lr > wave * 16 + kg4 + r) s[nt][r] = -__builtin_inff();
        }

        // online softmax, per q-row (reg r); row spread over 16 lanes of same group
#pragma unroll
        for (int r = 0; r < 4; ++r) {
            float pm = fmaxf(fmaxf(s[0][r], s[1][r]), fmaxf(s[2][r], s[3][r]));
#pragma unroll
            for (int off = 1; off < 16; off <<= 1) pm = fmaxf(pm, __shfl_xor(pm, off));
            float mnew = fmaxf(m[r], pm);
            float fac = __expf(m[r] - mnew);  // first iter: exp(-inf)=0
            float rs = 0.f;
#pragma unroll
            for (int nt = 0; nt < 4; ++nt) {
                float p = __expf(s[nt][r] - mnew);
                s[nt][r] = p;
                rs += p;
            }
#pragma unroll
            for (int off = 1; off < 16; off <<= 1) rs += __shfl_xor(rs, off);
            lsum[r] = lsum[r] * fac + rs;
            m[r] = mnew;
#pragma unroll
            for (int nt = 0; nt < 4; ++nt) o[nt][r] *= fac;
        }

        // P (D-layout) -> LDS -> A-layout for PV
#pragma unroll
        for (int nt = 0; nt < 4; ++nt)
#pragma unroll
            for (int r = 0; r < 4; ++r)
                sP[wave][(kg4 + r) * SP + nt * 16 + lr] = (bf16)s[nt][r];
        __syncthreads();

        // O += P V  (contraction over kv, 2 chunks of 32)
#pragma unroll
        for (int c = 0; c < 2; ++c) {
            const bf16* rp = &sP[wave][lr * SP + c * 32 + kg4];
            bf16x4 p0 = *(const bf16x4*)rp;
            bf16x4 p1 = *(const bf16x4*)(rp + 16);
            bf16x8 pf = __builtin_shufflevector(p0, p1, 0, 1, 2, 3, 4, 5, 6, 7);
#pragma unroll
            for (int nt = 0; nt < 4; ++nt) {
                const bf16* rv2 = &sVt[(nt * 16 + lr) * SV + c * 32 + kg4];
                bf16x4 v0 = *(const bf16x4*)rv2;
                bf16x4 v1 = *(const bf16x4*)(rv2 + 16);
                o[nt] = mfma16(pf,
                               __builtin_shufflevector(v0, v1, 0, 1, 2, 3, 4, 5, 6, 7),
                               o[nt]);
            }
        }
    }

    // epilogue: ob [B][T][H*64] bf16
#pragma unroll
    for (int r = 0; r < 4; ++r) {
        float inv = 1.f / lsum[r];
        int t = qt * 64 + wave * 16 + kg4 + r;
#pragma unroll
        for (int nt = 0; nt < 4; ++nt)
            ob[((size_t)(b * T_ + t)) * D_ + h * HD_ + nt * 16 + lr] =
                (bf16)(o[nt][r] * inv);
    }
}

// ---------------- launch ----------------
extern "C" void kernel_launch(void* const* d_in, const int* in_sizes, int n_in,
                              void* d_out, int out_size, void* d_ws, size_t ws_size,
                              hipStream_t stream) {
    const float* x = (const float*)d_in[0];
    const float* w_qkv = (const float*)d_in[1];
    const float* w_proj = (const float*)d_in[2];
    const float* b_proj = (const float*)d_in[3];
    float* out = (float*)d_out;
    char* ws = (char*)d_ws;

    // ws layout (bytes):
    bf16* xb = (bf16*)(ws);                    // [4096][1024]   8,388,608
    bf16* ob = (bf16*)(ws);                    // alias: attn out [4096][1024] (x consumed by GEMM1)
    bf16* wqkvt = (bf16*)(ws + 8388608);       // [3072][1024]   6,291,456
    bf16* wprojt = (bf16*)(ws + 14680064);     // [1024][1024]   2,097,152
    bf16* qbuf = (bf16*)(ws + 16777216);       // [B][H][T][64]  8,388,608
    bf16* kbuf = (bf16*)(ws + 25165824);       // same
    bf16* vbuf = (bf16*)(ws + 33554432);       // same; total 41,943,040

    cast_f32_bf16<<<4096, 256, 0, stream>>>(x, xb, (B_ * T_ * D_) / 4);
    dim3 tb(32, 8);
    cast_transpose<<<dim3(3 * D_ / 32, D_ / 32), tb, 0, stream>>>(w_qkv, wqkvt, D_, 3 * D_);
    cast_transpose<<<dim3(D_ / 32, D_ / 32), tb, 0, stream>>>(w_proj, wprojt, D_, D_);

    gemm_bt<0><<<dim3((B_ * T_) / 64, (3 * D_) / 64), 256, 0, stream>>>(
        xb, wqkvt, B_ * T_, 3 * D_, D_, qbuf, kbuf, vbuf, nullptr, nullptr);

    attn_kernel<<<dim3(T_ / 64, B_ * H_), 256, 0, stream>>>(qbuf, kbuf, vbuf, ob);

    gemm_bt<1><<<dim3((B_ * T_) / 64, D_ / 64), 256, 0, stream>>>(
        ob, wprojt, B_ * T_, D_, D_, nullptr, nullptr, nullptr, b_proj, out);
}